// Round 1
// baseline (277.835 us; speedup 1.0000x reference)
//
#include <hip/hip_runtime.h>
#include <math.h>

#define DIM_ 512
#define K_ 128
#define EPS_ 1e-6f
#define MARGIN_ 2.0f
#define PI_ 3.14159265358979f
#define QSTRIDE 68   // floats between consecutive tails' partial rows; 68%32=4 -> <=2-way bank aliasing (free)
#define HSTRIDE 520  // floats per precomputed-head row: 512 spatial + 4 scalars + pad (520*4 % 16 == 0)

__device__ __forceinline__ float frcp(float x) { return __builtin_amdgcn_rcpf(x); }

// Abramowitz-Stegun 4.4.45: |err| <= 6.7e-5 on [-1,1]
__device__ __forceinline__ float fast_acos(float x) {
    float ax = fabsf(x);
    float p = -0.0187293f;
    p = p * ax + 0.0742610f;
    p = p * ax - 0.2121144f;
    p = p * ax + 1.5707288f;
    float r = sqrtf(fmaxf(1.f - ax, 0.f)) * p;
    return x < 0.f ? PI_ - r : r;
}

__device__ __forceinline__ void fast_coshsinh(float x, float& c, float& s) {
    float e  = __expf(x);           // x <= ~25 here, no overflow
    float ei = frcp(e);
    c = 0.5f * (e + ei);
    s = 0.5f * (e - ei);
}

// expmap0 scalars from a = -t1^2 + sum_{i>=2} u_i^2 (u[0] forced 0)
__device__ __forceinline__ void expmap_cs(float a, float& c, float& s) {
    if (a > 0.f) {
        float sp = sqrtf(fmaxf(a, EPS_));
        float ch, sh;
        fast_coshsinh(sp, ch, sh);
        c = ch; s = sh * frcp(sp);
    } else {
        float st = sqrtf(fmaxf(-a, EPS_));
        c = __cosf(st);
        s = __sinf(st) * frcp(st);
    }
}

__device__ __forceinline__ void givens_rot(float gc, float gs, float& x0, float& x1) {
    float rn = frcp(fmaxf(sqrtf(gc * gc + gs * gs), 1e-15f));
    float c = gc * rn, s = gs * rn;
    float y0 = c * x0 - s * x1;
    float y1 = c * x1 + s * x0;
    x0 = y0; x1 = y1;
}

__device__ __forceinline__ void givens_ref(float gc, float gs, float& x0, float& x1) {
    float rn = frcp(fmaxf(sqrtf(gc * gc + gs * gs), 1e-15f));
    float c = gc * rn, s = gs * rn;
    float y0 = c * x0 + s * x1;
    float y1 = s * x0 - c * x1;
    x0 = y0; x1 = y1;
}

// ---------------------------------------------------------------------------
// Kernel 1: one wave per b. Full head pipeline (expmap0 -> rot_right -> boost
// -> reflect) computed ONCE per b instead of 16x, result written to workspace:
//   hws[b*HSTRIDE + 0..511]  = transformed head, dims 0,1 zeroed (spatial part)
//   hws[b*HSTRIDE + 512..515] = { hf0, hf1, nx, bias_head[u] }
// Lane l owns elements [4l,4l+4) and [256+4l,256+4l+4): all special indices
// (0,1,510,511; givens pairs) land on the same lanes as the 8l layout.
// ---------------------------------------------------------------------------
__global__ __launch_bounds__(256) void head_prep(
    const float* __restrict__ emb,        // [N_ENT, 512]
    const float* __restrict__ rel_boost,  // [N_REL, 2]
    const float* __restrict__ rot_left,   // [N_REL, 512]
    const float* __restrict__ rot_right,  // [N_REL, 512]
    const float* __restrict__ bias_head,  // [N_ENT]
    const int* __restrict__ u_idx,        // [B]
    const int* __restrict__ r_idx,        // [B]
    float* __restrict__ hws,              // [B, HSTRIDE]
    int B)
{
    const int lane = threadIdx.x & 63;
    const int wave = threadIdx.x >> 6;
    const int b = blockIdx.x * 4 + wave;
    if (b >= B) return;
    const int u = u_idx[b];
    const int r = r_idx[b];

    const float* hrow = emb + (size_t)u * DIM_ + lane * 4;
    float4 h0 = *(const float4*)hrow;
    float4 h1 = *(const float4*)(hrow + 256);
    const float* rr = rot_right + (size_t)r * DIM_ + lane * 4;
    float4 gr0 = *(const float4*)rr;
    float4 gr1 = *(const float4*)(rr + 256);
    const float* rl = rot_left + (size_t)r * DIM_ + lane * 4;
    float4 gl0 = *(const float4*)rl;
    float4 gl1 = *(const float4*)(rl + 256);
    const float rb0 = rel_boost[2*r];
    const float rb1 = rel_boost[2*r+1];
    const float bh = bias_head[u];

    // ---- expmap0 ----
    if (lane == 0) h0.x = 0.f;              // proj_tan0 (element 0)
    float ps = h0.x*h0.x + h0.y*h0.y + h0.z*h0.z + h0.w*h0.w
             + h1.x*h1.x + h1.y*h1.y + h1.z*h1.z + h1.w*h1.w;
#pragma unroll
    for (int off = 32; off >= 1; off >>= 1) ps += __shfl_xor(ps, off, 64);
    float u1 = __shfl(h0.y, 0, 64);         // element 1
    float a = ps - 2.f * u1 * u1;           // -u1^2 + sum_{i>=2} u_i^2
    float ch, sh;
    expmap_cs(a, ch, sh);
    h0.x *= sh; h0.y *= sh; h0.z *= sh; h0.w *= sh;
    h1.x *= sh; h1.y *= sh; h1.z *= sh; h1.w *= sh;
    if (lane == 0) h0.x = ch;               // out[0] = c

    // ---- givens rotation (rot_right): pairs (4l,4l+1),(4l+2,4l+3),(256+4l,...) ----
    givens_rot(gr0.x, gr0.y, h0.x, h0.y);
    givens_rot(gr0.z, gr0.w, h0.z, h0.w);
    givens_rot(gr1.x, gr1.y, h1.x, h1.y);
    givens_rot(gr1.z, gr1.w, h1.z, h1.w);

    // ---- boost: mixes dims {0,510} and {1,511} ----
    {
        float bb0 = __logf(1.f + __expf(rb0));
        float bb1 = __logf(1.f + __expf(rb1));
        float C0 = sqrtf(1.f + bb0*bb0);
        float C1 = sqrtf(1.f + bb1*bb1);
        float e0   = __shfl(h0.x, 0, 64);   // elem 0
        float e1   = __shfl(h0.y, 0, 64);   // elem 1
        float e510 = __shfl(h1.z, 63, 64);  // elem 256+4*63+2 = 510
        float e511 = __shfl(h1.w, 63, 64);  // elem 511
        if (lane == 0) {
            h0.x = C0*e0 - bb0*e510;
            h0.y = C1*e1 - bb1*e511;
        }
        if (lane == 63) {
            h1.z = C0*e510 - bb0*e0;
            h1.w = C1*e511 - bb1*e1;
        }
    }

    // ---- givens reflection (rot_left) ----
    givens_ref(gl0.x, gl0.y, h0.x, h0.y);
    givens_ref(gl0.z, gl0.w, h0.z, h0.w);
    givens_ref(gl1.x, gl1.y, h1.x, h1.y);
    givens_ref(gl1.z, gl1.w, h1.z, h1.w);

    // ---- head scalars + zero time dims for the spatial dot ----
    float hf0 = __shfl(h0.x, 0, 64);
    float hf1 = __shfl(h0.y, 0, 64);
    float nx = sqrtf(hf0*hf0 + hf1*hf1);
    if (lane == 0) { h0.x = 0.f; h0.y = 0.f; }

    float* o = hws + (size_t)b * HSTRIDE;
    *(float4*)(o + lane * 4) = h0;
    *(float4*)(o + 256 + lane * 4) = h1;
    if (lane == 0) {
        float4 sc = make_float4(hf0, hf1, nx, bh);
        *(float4*)(o + 512) = sc;
    }
}

// ---------------------------------------------------------------------------
// Kernel 2: grid (B, 4) x 256 threads: 4 waves/block, 8 tails/wave.
// Pure gather + dot kernel: no rot loads, no head transcendentals, no long
// shfl chains before the payload. Lane l owns elements [4l,4l+4) and
// [256+4l,256+4l+4) of every 512-dim row -> each load instruction covers a
// fully contiguous 1KB (vs 16B-every-32B before: halves L1 line requests).
// ---------------------------------------------------------------------------
__global__ __launch_bounds__(256) void ultrae_main(
    const float* __restrict__ emb,        // [N_ENT, 512]
    const float* __restrict__ bias_tail,  // [N_ENT]
    const int* __restrict__ v_idx,        // [B, K]
    const float* __restrict__ hws,        // [B, HSTRIDE]
    float* __restrict__ out)              // [B, K]
{
    __shared__ float lds_q[4][8 * QSTRIDE + 4];
    __shared__ float lds_d[4][8 * QSTRIDE + 4];
    __shared__ float lds_t[4][8];

    const int b = blockIdx.x;
    const int lane = threadIdx.x & 63;
    const int wave = threadIdx.x >> 6;

    // ---- issue ALL global loads first (max memory-level parallelism) ----
    const int kbase = (blockIdx.y * 4 + wave) * 8;
    const int* vp = v_idx + b * K_ + kbase;
    const int4 vv0 = *(const int4*)(vp);
    const int4 vv1 = *(const int4*)(vp + 4);

    const float* hb = hws + (size_t)b * HSTRIDE;
    float4 h0 = *(const float4*)(hb + lane * 4);
    float4 h1 = *(const float4*)(hb + 256 + lane * 4);
    const float4 sc = *(const float4*)(hb + 512);   // { hf0, hf1, nx, bh }

    const int vi[8] = {vv0.x, vv0.y, vv0.z, vv0.w, vv1.x, vv1.y, vv1.z, vv1.w};
    float4 t0[8], t1[8];
#pragma unroll
    for (int j = 0; j < 8; ++j) {
        const float* trow = emb + (size_t)vi[j] * DIM_ + lane * 4;
        t0[j] = *(const float4*)trow;
        t1[j] = *(const float4*)(trow + 256);
    }

    // per-lane tail for the lane-parallel scalar phase: lane handles tail m = lane&7
    const int m = lane & 7;
    const int g = lane >> 3;
    float bt = 0.f;
    if (lane < 8) bt = bias_tail[vp[m]];   // only the 8 storing lanes need it

    // ---- stash raw tail element 1 (lane 0's t0[j].y) for the scalar phase ----
    if (lane == 0) {
#pragma unroll
        for (int j = 0; j < 8; ++j) lds_t[wave][j] = t0[j].y;
    }

    // ---- per-lane (q,d) partials for all 8 tails -> LDS ----
#pragma unroll
    for (int j = 0; j < 8; ++j) {
        float4 s0 = t0[j], s1 = t1[j];
        if (lane == 0) { s0.x = 0.f; s0.y = 0.f; }   // exclude dims 0,1 from q
        float qp = s0.x*s0.x + s0.y*s0.y + s0.z*s0.z + s0.w*s0.w
                 + s1.x*s1.x + s1.y*s1.y + s1.z*s1.z + s1.w*s1.w;
        float dp = h0.x*s0.x + h0.y*s0.y + h0.z*s0.z + h0.w*s0.w   // h dims 0,1 pre-zeroed
                 + h1.x*s1.x + h1.y*s1.y + h1.z*s1.z + h1.w*s1.w;
        lds_q[wave][j * QSTRIDE + lane] = qp;
        lds_d[wave][j * QSTRIDE + lane] = dp;
    }

    // DS ops within a wave execute in order; barrier only pins compiler scheduling.
    __builtin_amdgcn_wave_barrier();

    // ---- transposed accumulate: lane (m,g) sums partials p = g+8k of tail m ----
    float q = 0.f, d = 0.f;
    const float* qa = &lds_q[wave][m * QSTRIDE + g];
    const float* da = &lds_d[wave][m * QSTRIDE + g];
#pragma unroll
    for (int k = 0; k < 8; ++k) {
        q += qa[8 * k];
        d += da[8 * k];
    }
    // finish across the g dimension (lanes differing in bits 3..5)
    q += __shfl_xor(q, 8, 64);  d += __shfl_xor(d, 8, 64);
    q += __shfl_xor(q, 16, 64); d += __shfl_xor(d, 16, 64);
    q += __shfl_xor(q, 32, 64); d += __shfl_xor(d, 32, 64);

    const float tt1 = lds_t[wave][m];       // broadcast read, conflict-free

    // ---- per-tail scalar math, 8-way lane-parallel (tail m per lane) ----
    const float hf0 = sc.x, hf1 = sc.y, nx = sc.z, bh = sc.w;
    const float rnx = frcp(nx);
    float at = q - tt1 * tt1;               // -t1^2 + sum_{i>=2} t_i^2
    float ct, st;
    expmap_cs(at, ct, st);
    float yt1 = st * tt1;                   // tail time = (ct, st*t1)
    float ny = sqrtf(ct*ct + yt1*yt1);
    float cosang = (hf0*ct + hf1*yt1) * rnx * frcp(ny);
    cosang = fminf(fmaxf(cosang, -1.f + EPS_), 1.f - EPS_);
    float dsph = fminf(nx, ny) * fast_acos(cosang);   // min(c1,c2) folds here
    float inner = fmaxf(nx*ny - st*d, 1.f + EPS_);
    // acosh(x) = log(x + sqrt(x-1)*sqrt(x+1)) — factored sqrts avoid x^2 overflow
    float dhyp = __logf(inner + sqrtf(inner - 1.f) * sqrtf(inner + 1.f));
    float dsum = dsph + dhyp;
    if (lane < 8) {
        out[b * K_ + kbase + m] = MARGIN_ - dsum*dsum + bh + bt;
    }
}

extern "C" void kernel_launch(void* const* d_in, const int* in_sizes, int n_in,
                              void* d_out, int out_size, void* d_ws, size_t ws_size,
                              hipStream_t stream) {
    const float* emb       = (const float*)d_in[0];
    const float* rel_boost = (const float*)d_in[1];
    const float* rot_left  = (const float*)d_in[2];
    const float* rot_right = (const float*)d_in[3];
    const float* bias_h    = (const float*)d_in[4];
    const float* bias_t    = (const float*)d_in[5];
    const int* u_idx       = (const int*)d_in[6];
    const int* r_idx       = (const int*)d_in[7];
    const int* v_idx       = (const int*)d_in[8];
    float* out = (float*)d_out;
    float* hws = (float*)d_ws;            // B*HSTRIDE floats = ~1.06 MB << ws_size

    int B = in_sizes[6];                  // 512

    dim3 gprep((B + 3) / 4), bprep(256);
    hipLaunchKernelGGL(head_prep, gprep, bprep, 0, stream,
                       emb, rel_boost, rot_left, rot_right,
                       bias_h, u_idx, r_idx, hws, B);

    dim3 grid(B, 4), block(256);
    hipLaunchKernelGGL(ultrae_main, grid, block, 0, stream,
                       emb, bias_t, v_idx, hws, out);
}

// Round 2
// 273.457 us; speedup vs baseline: 1.0160x; 1.0160x over previous
//
#include <hip/hip_runtime.h>
#include <math.h>

#define DIM_ 512
#define K_ 128
#define EPS_ 1e-6f
#define MARGIN_ 2.0f
#define PI_ 3.14159265358979f
#define QSTRIDE 68   // floats between consecutive tails' partial rows; 68%32=4 -> <=2-way bank aliasing (free)

__device__ __forceinline__ float frcp(float x) { return __builtin_amdgcn_rcpf(x); }

// Abramowitz-Stegun 4.4.45: |err| <= 6.7e-5 on [-1,1]
__device__ __forceinline__ float fast_acos(float x) {
    float ax = fabsf(x);
    float p = -0.0187293f;
    p = p * ax + 0.0742610f;
    p = p * ax - 0.2121144f;
    p = p * ax + 1.5707288f;
    float r = sqrtf(fmaxf(1.f - ax, 0.f)) * p;
    return x < 0.f ? PI_ - r : r;
}

__device__ __forceinline__ void fast_coshsinh(float x, float& c, float& s) {
    float e  = __expf(x);           // x <= ~25 here, no overflow
    float ei = frcp(e);
    c = 0.5f * (e + ei);
    s = 0.5f * (e - ei);
}

// expmap0 scalars from a = -t1^2 + sum_{i>=2} u_i^2 (u[0] forced 0)
__device__ __forceinline__ void expmap_cs(float a, float& c, float& s) {
    if (a > 0.f) {
        float sp = sqrtf(fmaxf(a, EPS_));
        float ch, sh;
        fast_coshsinh(sp, ch, sh);
        c = ch; s = sh * frcp(sp);
    } else {
        float st = sqrtf(fmaxf(-a, EPS_));
        c = __cosf(st);
        s = __sinf(st) * frcp(st);
    }
}

__device__ __forceinline__ void givens_rot(float gc, float gs, float& x0, float& x1) {
    float rn = frcp(fmaxf(sqrtf(gc * gc + gs * gs), 1e-15f));
    float c = gc * rn, s = gs * rn;
    float y0 = c * x0 - s * x1;
    float y1 = c * x1 + s * x0;
    x0 = y0; x1 = y1;
}

__device__ __forceinline__ void givens_ref(float gc, float gs, float& x0, float& x1) {
    float rn = frcp(fmaxf(sqrtf(gc * gc + gs * gs), 1e-15f));
    float c = gc * rn, s = gs * rn;
    float y0 = c * x0 + s * x1;
    float y1 = s * x0 - c * x1;
    x0 = y0; x1 = y1;
}

// Single dispatch: grid (B, 4) x 256 threads: 4 waves/block, 8 tails/wave.
// Head pipeline computed redundantly per wave (overlaps with tail-load
// latency; measured free vs. a separate serialized prep dispatch).
// Lane l owns elements [4l,4l+4) and [256+4l,256+4l+4) of every 512-dim row,
// so each dwordx4 instruction covers a fully contiguous 1 KB wave access.
// Special indices (0,1,510,511; all givens pairs) stay intra-lane:
//   elem0 = lane0.h0.x, elem1 = lane0.h0.y, elem510 = lane63.h1.z, elem511 = lane63.h1.w
__global__ __launch_bounds__(256) void ultrae_kernel(
    const float* __restrict__ emb,        // [N_ENT, 512]
    const float* __restrict__ rel_boost,  // [N_REL, 2]
    const float* __restrict__ rot_left,   // [N_REL, 512]
    const float* __restrict__ rot_right,  // [N_REL, 512]
    const float* __restrict__ bias_head,  // [N_ENT]
    const float* __restrict__ bias_tail,  // [N_ENT]
    const int* __restrict__ u_idx,        // [B]
    const int* __restrict__ r_idx,        // [B]
    const int* __restrict__ v_idx,        // [B, K]
    float* __restrict__ out)              // [B, K]
{
    __shared__ float lds_q[4][8 * QSTRIDE + 4];
    __shared__ float lds_d[4][8 * QSTRIDE + 4];
    __shared__ float lds_t[4][8];

    const int b = blockIdx.x;
    const int lane = threadIdx.x & 63;
    const int wave = threadIdx.x >> 6;
    const int u = u_idx[b];
    const int r = r_idx[b];

    // ---- issue ALL global loads first (max memory-level parallelism) ----
    const int kbase = (blockIdx.y * 4 + wave) * 8;
    const int* vp = v_idx + b * K_ + kbase;
    const int4 vv0 = *(const int4*)(vp);
    const int4 vv1 = *(const int4*)(vp + 4);
    const int vi[8] = {vv0.x, vv0.y, vv0.z, vv0.w, vv1.x, vv1.y, vv1.z, vv1.w};
    float4 t0[8], t1[8];
#pragma unroll
    for (int j = 0; j < 8; ++j) {
        const float* trow = emb + (size_t)vi[j] * DIM_ + lane * 4;
        t0[j] = *(const float4*)trow;
        t1[j] = *(const float4*)(trow + 256);
    }

    const float* hrow = emb + (size_t)u * DIM_ + lane * 4;
    float4 h0 = *(const float4*)hrow;
    float4 h1 = *(const float4*)(hrow + 256);
    const float* rr = rot_right + (size_t)r * DIM_ + lane * 4;
    float4 gr0 = *(const float4*)rr;
    float4 gr1 = *(const float4*)(rr + 256);
    const float* rl = rot_left + (size_t)r * DIM_ + lane * 4;
    float4 gl0 = *(const float4*)rl;
    float4 gl1 = *(const float4*)(rl + 256);
    const float rb0 = rel_boost[2*r];
    const float rb1 = rel_boost[2*r+1];
    const float bh = bias_head[u];

    // per-lane tail for the lane-parallel scalar phase: lane handles tail m = lane&7
    const int m = lane & 7;
    const int g = lane >> 3;
    float bt = 0.f;
    if (lane < 8) bt = bias_tail[vp[m]];   // only the 8 storing lanes need it

    // ---- head: expmap0 ----
    if (lane == 0) h0.x = 0.f;              // proj_tan0 (element 0)
    float ps = h0.x*h0.x + h0.y*h0.y + h0.z*h0.z + h0.w*h0.w
             + h1.x*h1.x + h1.y*h1.y + h1.z*h1.z + h1.w*h1.w;
#pragma unroll
    for (int off = 32; off >= 1; off >>= 1) ps += __shfl_xor(ps, off, 64);
    float u1 = __shfl(h0.y, 0, 64);         // element 1
    float a = ps - 2.f * u1 * u1;           // -u1^2 + sum_{i>=2} u_i^2
    float ch, sh;
    expmap_cs(a, ch, sh);
    h0.x *= sh; h0.y *= sh; h0.z *= sh; h0.w *= sh;
    h1.x *= sh; h1.y *= sh; h1.z *= sh; h1.w *= sh;
    if (lane == 0) h0.x = ch;               // out[0] = c

    // ---- givens rotation (rot_right): pairs (4l,4l+1),(4l+2,4l+3),(256+...) ----
    givens_rot(gr0.x, gr0.y, h0.x, h0.y);
    givens_rot(gr0.z, gr0.w, h0.z, h0.w);
    givens_rot(gr1.x, gr1.y, h1.x, h1.y);
    givens_rot(gr1.z, gr1.w, h1.z, h1.w);

    // ---- boost: mixes dims {0,510} and {1,511} ----
    {
        float bb0 = __logf(1.f + __expf(rb0));
        float bb1 = __logf(1.f + __expf(rb1));
        float C0 = sqrtf(1.f + bb0*bb0);
        float C1 = sqrtf(1.f + bb1*bb1);
        float e0   = __shfl(h0.x, 0, 64);   // elem 0
        float e1   = __shfl(h0.y, 0, 64);   // elem 1
        float e510 = __shfl(h1.z, 63, 64);  // elem 510
        float e511 = __shfl(h1.w, 63, 64);  // elem 511
        if (lane == 0) {
            h0.x = C0*e0 - bb0*e510;
            h0.y = C1*e1 - bb1*e511;
        }
        if (lane == 63) {
            h1.z = C0*e510 - bb0*e0;
            h1.w = C1*e511 - bb1*e1;
        }
    }

    // ---- givens reflection (rot_left) ----
    givens_ref(gl0.x, gl0.y, h0.x, h0.y);
    givens_ref(gl0.z, gl0.w, h0.z, h0.w);
    givens_ref(gl1.x, gl1.y, h1.x, h1.y);
    givens_ref(gl1.z, gl1.w, h1.z, h1.w);

    // ---- head scalars ----
    float hf0 = __shfl(h0.x, 0, 64);
    float hf1 = __shfl(h0.y, 0, 64);
    float nx = sqrtf(hf0*hf0 + hf1*hf1);
    if (lane == 0) { h0.x = 0.f; h0.y = 0.f; }   // spatial dot excludes dims 0,1
    const float rnx = frcp(nx);

    // ---- stash raw tail element 1 (lane 0's t0[j].y) for the scalar phase ----
    if (lane == 0) {
#pragma unroll
        for (int j = 0; j < 8; ++j) lds_t[wave][j] = t0[j].y;
    }

    // ---- per-lane (q,d) partials for all 8 tails -> LDS ----
#pragma unroll
    for (int j = 0; j < 8; ++j) {
        float4 s0 = t0[j], s1 = t1[j];
        if (lane == 0) { s0.x = 0.f; s0.y = 0.f; }   // exclude dims 0,1 from q
        float qp = s0.x*s0.x + s0.y*s0.y + s0.z*s0.z + s0.w*s0.w
                 + s1.x*s1.x + s1.y*s1.y + s1.z*s1.z + s1.w*s1.w;
        float dp = h0.x*s0.x + h0.y*s0.y + h0.z*s0.z + h0.w*s0.w
                 + h1.x*s1.x + h1.y*s1.y + h1.z*s1.z + h1.w*s1.w;
        lds_q[wave][j * QSTRIDE + lane] = qp;
        lds_d[wave][j * QSTRIDE + lane] = dp;
    }

    // DS ops within a wave execute in order; barrier only pins compiler scheduling.
    __builtin_amdgcn_wave_barrier();

    // ---- transposed accumulate: lane (m,g) sums partials p = g+8k of tail m ----
    float q = 0.f, d = 0.f;
    const float* qa = &lds_q[wave][m * QSTRIDE + g];
    const float* da = &lds_d[wave][m * QSTRIDE + g];
#pragma unroll
    for (int k = 0; k < 8; ++k) {
        q += qa[8 * k];
        d += da[8 * k];
    }
    // finish across the g dimension (lanes differing in bits 3..5)
    q += __shfl_xor(q, 8, 64);  d += __shfl_xor(d, 8, 64);
    q += __shfl_xor(q, 16, 64); d += __shfl_xor(d, 16, 64);
    q += __shfl_xor(q, 32, 64); d += __shfl_xor(d, 32, 64);

    const float tt1 = lds_t[wave][m];       // broadcast read, conflict-free

    // ---- per-tail scalar math, 8-way lane-parallel (tail m per lane) ----
    float at = q - tt1 * tt1;               // -t1^2 + sum_{i>=2} t_i^2
    float ct, st;
    expmap_cs(at, ct, st);
    float yt1 = st * tt1;                   // tail time = (ct, st*t1)
    float ny = sqrtf(ct*ct + yt1*yt1);
    float cosang = (hf0*ct + hf1*yt1) * rnx * frcp(ny);
    cosang = fminf(fmaxf(cosang, -1.f + EPS_), 1.f - EPS_);
    float dsph = fminf(nx, ny) * fast_acos(cosang);   // min(c1,c2) folds here
    float inner = fmaxf(nx*ny - st*d, 1.f + EPS_);
    // acosh(x) = log(x + sqrt(x-1)*sqrt(x+1)) — factored sqrts avoid x^2 overflow
    float dhyp = __logf(inner + sqrtf(inner - 1.f) * sqrtf(inner + 1.f));
    float dsum = dsph + dhyp;
    if (lane < 8) {
        out[b * K_ + kbase + m] = MARGIN_ - dsum*dsum + bh + bt;
    }
}

extern "C" void kernel_launch(void* const* d_in, const int* in_sizes, int n_in,
                              void* d_out, int out_size, void* d_ws, size_t ws_size,
                              hipStream_t stream) {
    const float* emb       = (const float*)d_in[0];
    const float* rel_boost = (const float*)d_in[1];
    const float* rot_left  = (const float*)d_in[2];
    const float* rot_right = (const float*)d_in[3];
    const float* bias_h    = (const float*)d_in[4];
    const float* bias_t    = (const float*)d_in[5];
    const int* u_idx       = (const int*)d_in[6];
    const int* r_idx       = (const int*)d_in[7];
    const int* v_idx       = (const int*)d_in[8];
    float* out = (float*)d_out;

    int B = in_sizes[6];           // 512
    dim3 grid(B, 4), block(256);
    hipLaunchKernelGGL(ultrae_kernel, grid, block, 0, stream,
                       emb, rel_boost, rot_left, rot_right,
                       bias_h, bias_t, u_idx, r_idx, v_idx, out);
}